// Round 17
// baseline (199.720 us; speedup 1.0000x reference)
//
#include <hip/hip_runtime.h>
#include <math.h>

#define B_   32
#define N_   128
#define H_   100
#define ROWS (B_ * N_)    // 4096
#define RH   (ROWS * H_)  // 409600
#define OUTSZ (B_ * H_)   // 3200

// ---------------------------------------------------------------------------
// K1: hw = nodes@Ww ONLY (initial hv is computed in-register by pass 1 from
// its staged hid_s — row-local). Also zero-initializes out.
__global__ __launch_bounds__(256, 6) void k_proj0(const float* __restrict__ nodes,
                                                  const float* __restrict__ Ww,
                                                  float* __restrict__ hw,
                                                  float* __restrict__ out) {
    __shared__ float nod_s[2][H_];
    const int row0 = blockIdx.x * 2;
    const int t = threadIdx.x, r = t >> 7, j = t & 127;
    {   // zero out[] (3 dispatches before any atomicAdd; stream-ordered)
        const int gid = blockIdx.x * 256 + t;
        if (gid < OUTSZ) out[gid] = 0.f;
    }
    {
        const float4* ng = (const float4*)(nodes + (size_t)row0 * H_);
        if (t < 50) ((float4*)nod_s)[t] = ng[t];
    }
    __syncthreads();
    if (j >= H_) return;
    const float4* h4p = (const float4*)nod_s[r];
    float wa = 0.f;
#pragma unroll 5
    for (int k4 = 0; k4 < 25; ++k4) {
        const float4 h4 = h4p[k4];
        const int k = k4 * 4;
        wa = fmaf(h4.x, Ww[(k + 0) * H_ + j], wa);
        wa = fmaf(h4.y, Ww[(k + 1) * H_ + j], wa);
        wa = fmaf(h4.z, Ww[(k + 2) * H_ + j], wa);
        wa = fmaf(h4.w, Ww[(k + 3) * H_ + j], wa);
    }
    hw[(size_t)(row0 + r) * H_ + j] = wa;
}

// ---------------------------------------------------------------------------
// K2: one fused message pass (r13 structure, launch_bounds(256,6)).
// MODE / INIT_HV are COMPILE-TIME template params: each dispatch gets a
// branch-free specialized body (r16's runtime branches slowed all passes
// 45->51 us at identical VGPR/occupancy — codegen, not algorithm).
// 2 rows per 256-thread block (r = t>>7, j = t&127, lane j = h).
// Message loop: e_s b128 broadcast + ballot-bit SGPR mask + coalesced hw.
// MODE 1 -> tanh update + next-pass hv/hw projections; MODE 2 -> readout.
template <int MODE, int INIT_HV>
__global__ __launch_bounds__(256, 6) void k_pass(const float* __restrict__ edges,
                                                 const float* __restrict__ We,
                                                 const float* __restrict__ Wu,
                                                 const float* __restrict__ Wv,
                                                 const float* __restrict__ Ww,
                                                 const float* __restrict__ Wr,
                                                 const float* __restrict__ nodes,
                                                 float* __restrict__ hv_io,
                                                 const float* __restrict__ hw_in,
                                                 float* __restrict__ hw_out,
                                                 const float* __restrict__ hid_in,
                                                 float* __restrict__ hidden,
                                                 float* __restrict__ out) {
    __shared__ float4 e_s[2][N_];          // 4 KB
    __shared__ float  asum_part[4];        // per-wave partial row sums
    __shared__ unsigned qmask_s[2][4];     // per-row edge-mask bits (4x32)
    __shared__ float  hid_s[2][H_];
    __shared__ float  msg_s[2][H_];
    __shared__ float  hn_s[2][H_];
    __shared__ float  nod_s[2][H_];        // MODE 2 only
    __shared__ float  red_s[2][H_];        // MODE 2 only

    const int row0 = blockIdx.x * 2;
    const int b = row0 >> 7;
    const int t = threadIdx.x, r = t >> 7, j = t & 127;
    const int wv = t >> 6, lane = t & 63;
    const int row = row0 + r;
    const bool act = (j < H_);

    {   // stage both rows' edges; ballot edge-mask bits; reduce row sums
        const float4* eg = (const float4*)(edges + (size_t)row0 * N_ * 4);
        const float4 e = eg[t];                   // t == r*128 + j, coalesced
        e_s[r][j] = e;                            // wave wv, lane l -> w = (wv&1)*64 + l
        float s = (e.x + e.y) + (e.z + e.w);
        const unsigned long long bal = __ballot(s != 0.f);
        if (lane == 0) {
            qmask_s[wv >> 1][(wv & 1) * 2]     = (unsigned)bal;
            qmask_s[wv >> 1][(wv & 1) * 2 + 1] = (unsigned)(bal >> 32);
        }
#pragma unroll
        for (int off = 32; off > 0; off >>= 1) s += __shfl_down(s, off);
        if (lane == 0) asum_part[wv] = s;
    }
    {   // stage pre-update hidden rows (50 float4); nodes too if readout pass
        const float4* hg = (const float4*)(hid_in + (size_t)row0 * H_);
        if (t < 50) ((float4*)hid_s)[t] = hg[t];
        if (MODE == 2) {
            const float4* ng = (const float4*)(nodes + (size_t)row0 * H_);
            if (t < 50) ((float4*)nod_s)[t] = ng[t];
        }
    }
    __syncthreads();

    const float nm = ((asum_part[2 * r] + asum_part[2 * r + 1]) != 0.f) ? 1.f : 0.f;

    if (act) {
        float hvv;
        if (INIT_HV) {      // pass 1: hv = hid @ Wv computed in-register
            const float4* h4p = (const float4*)hid_s[r];
            float va = 0.f;
#pragma unroll 5
            for (int k4 = 0; k4 < 25; ++k4) {
                const float4 h4 = h4p[k4];
                const int k = k4 * 4;
                va = fmaf(h4.x, Wv[(k + 0) * H_ + j], va);
                va = fmaf(h4.y, Wv[(k + 1) * H_ + j], va);
                va = fmaf(h4.z, Wv[(k + 2) * H_ + j], va);
                va = fmaf(h4.w, Wv[(k + 3) * H_ + j], va);
            }
            hvv = va;
        } else {
            hvv = hv_io[(size_t)row * H_ + j];
        }
        const float we0 = We[0 * H_ + j], we1 = We[1 * H_ + j];
        const float we2 = We[2 * H_ + j], we3 = We[3 * H_ + j];
        const float* hwp = hw_in + (size_t)b * N_ * H_ + j;
        float acc = 0.f;
        for (int c = 0; c < 4; ++c) {             // 4 chunks of 32 w
            const unsigned mq =
                __builtin_amdgcn_readfirstlane(qmask_s[r][c]);  // SGPR, uniform
            const float4* ec = &e_s[r][c * 32];
            const float*  hc = hwp + (size_t)(c * 32) * H_;
#pragma unroll 8
            for (int w8 = 0; w8 < 32; ++w8) {
                const float4 e = ec[w8];          // LDS b128 broadcast
                const float  hww = hc[w8 * H_];   // coalesced 400B/wave-pair
                const float  m = ((mq >> w8) & 1u) ? 1.f : 0.f;  // SALU cselect
                float p = hvv + hww;
                p = fmaf(e.x, we0, p);
                p = fmaf(e.y, we1, p);
                p = fmaf(e.z, we2, p);
                p = fmaf(e.w, we3, p);
                acc = fmaf(m, fmaxf(p, 0.f), acc);
            }
        }
        msg_s[r][j] = acc;
    }
    __syncthreads();

    if (act) {
        const float4* h4p = (const float4*)hid_s[r];
        const float4* m4p = (const float4*)msg_s[r];
        float u = 0.f;
#pragma unroll 5
        for (int k4 = 0; k4 < 25; ++k4) {
            const float4 h4 = h4p[k4];
            const int k = k4 * 4;
            u = fmaf(h4.x, Wu[(k + 0) * H_ + j], u);
            u = fmaf(h4.y, Wu[(k + 1) * H_ + j], u);
            u = fmaf(h4.z, Wu[(k + 2) * H_ + j], u);
            u = fmaf(h4.w, Wu[(k + 3) * H_ + j], u);
        }
#pragma unroll 5
        for (int k4 = 0; k4 < 25; ++k4) {
            const float4 m4 = m4p[k4];
            const int k = H_ + k4 * 4;
            u = fmaf(m4.x, Wu[(k + 0) * H_ + j], u);
            u = fmaf(m4.y, Wu[(k + 1) * H_ + j], u);
            u = fmaf(m4.z, Wu[(k + 2) * H_ + j], u);
            u = fmaf(m4.w, Wu[(k + 3) * H_ + j], u);
        }
        const float nh = (nm != 0.f) ? tanhf(u) : hid_s[r][j];
        hn_s[r][j] = nh;
        if (MODE == 1) hidden[(size_t)row * H_ + j] = nh;
    }
    __syncthreads();

    if (MODE == 1) {        // next pass's hv/hw from fresh hidden (own rows)
        if (act) {
            const float4* h4p = (const float4*)hn_s[r];
            float va = 0.f, wa = 0.f;
#pragma unroll 5
            for (int k4 = 0; k4 < 25; ++k4) {
                const float4 h4 = h4p[k4];
                const int k = k4 * 4;
                va = fmaf(h4.x, Wv[(k + 0) * H_ + j], va);
                wa = fmaf(h4.x, Ww[(k + 0) * H_ + j], wa);
                va = fmaf(h4.y, Wv[(k + 1) * H_ + j], va);
                wa = fmaf(h4.y, Ww[(k + 1) * H_ + j], wa);
                va = fmaf(h4.z, Wv[(k + 2) * H_ + j], va);
                wa = fmaf(h4.z, Ww[(k + 2) * H_ + j], wa);
                va = fmaf(h4.w, Wv[(k + 3) * H_ + j], va);
                wa = fmaf(h4.w, Ww[(k + 3) * H_ + j], wa);
            }
            hv_io[(size_t)row * H_ + j] = va;     // row-local: safe in-place
            hw_out[(size_t)row * H_ + j] = wa;    // double-buffered
        }
    } else {                // MODE 2: fused readout
        if (act) {
            const float4* h4p = (const float4*)hn_s[r];
            const float4* n4p = (const float4*)nod_s[r];
            float u = 0.f;
#pragma unroll 5
            for (int k4 = 0; k4 < 25; ++k4) {
                const float4 h4 = h4p[k4];
                const int k = k4 * 4;
                u = fmaf(h4.x, Wr[(k + 0) * H_ + j], u);
                u = fmaf(h4.y, Wr[(k + 1) * H_ + j], u);
                u = fmaf(h4.z, Wr[(k + 2) * H_ + j], u);
                u = fmaf(h4.w, Wr[(k + 3) * H_ + j], u);
            }
#pragma unroll 5
            for (int k4 = 0; k4 < 25; ++k4) {
                const float4 n4 = n4p[k4];
                const int k = H_ + k4 * 4;
                u = fmaf(n4.x, Wr[(k + 0) * H_ + j], u);
                u = fmaf(n4.y, Wr[(k + 1) * H_ + j], u);
                u = fmaf(n4.z, Wr[(k + 2) * H_ + j], u);
                u = fmaf(n4.w, Wr[(k + 3) * H_ + j], u);
            }
            red_s[r][j] = nm * fmaxf(u, 0.f);
        }
        __syncthreads();
        if (t < H_) atomicAdd(out + b * H_ + t, red_s[0][t] + red_s[1][t]);
    }
}

// ---------------------------------------------------------------------------
extern "C" void kernel_launch(void* const* d_in, const int* in_sizes, int n_in,
                              void* d_out, int out_size, void* d_ws, size_t ws_size,
                              hipStream_t stream) {
    const float* nodes = (const float*)d_in[0];
    const float* edges = (const float*)d_in[1];
    const float* Wv    = (const float*)d_in[2];
    const float* Ww    = (const float*)d_in[3];
    const float* We    = (const float*)d_in[4];
    const float* Wu    = (const float*)d_in[5];
    const float* Wr    = (const float*)d_in[6];
    float* out = (float*)d_out;

    float* hidden = (float*)d_ws;     // RH
    float* hv     = hidden + RH;      // RH
    float* hwA    = hv + RH;          // RH
    float* hwB    = hwA + RH;         // RH

    k_proj0<<<ROWS / 2, 256, 0, stream>>>(nodes, Ww, hwA, out);

    k_pass<1, 1><<<ROWS / 2, 256, 0, stream>>>(edges, We, Wu, Wv, Ww, Wr, nodes,
                                               hv, hwA, hwB, nodes, hidden, out);
    k_pass<1, 0><<<ROWS / 2, 256, 0, stream>>>(edges, We, Wu, Wv, Ww, Wr, nodes,
                                               hv, hwB, hwA, hidden, hidden, out);
    k_pass<2, 0><<<ROWS / 2, 256, 0, stream>>>(edges, We, Wu, Wv, Ww, Wr, nodes,
                                               hv, hwA, hwB, hidden, hidden, out);
}

// Round 18
// 192.237 us; speedup vs baseline: 1.0389x; 1.0389x over previous
//
#include <hip/hip_runtime.h>
#include <math.h>

#define B_   32
#define N_   128
#define H_   100
#define ROWS (B_ * N_)    // 4096
#define RH   (ROWS * H_)  // 409600
#define OUTSZ (B_ * H_)   // 3200

// ---------------------------------------------------------------------------
// K1: hw = nodes@Ww ONLY (initial hv computed in-register by pass 1).
// Also zero-initializes out.
__global__ __launch_bounds__(256, 6) void k_proj0(const float* __restrict__ nodes,
                                                  const float* __restrict__ Ww,
                                                  float* __restrict__ hw,
                                                  float* __restrict__ out) {
    __shared__ float nod_s[2][H_];
    const int row0 = blockIdx.x * 2;
    const int t = threadIdx.x, r = t >> 7, j = t & 127;
    {   // zero out[] (3 dispatches before any atomicAdd; stream-ordered)
        const int gid = blockIdx.x * 256 + t;
        if (gid < OUTSZ) out[gid] = 0.f;
    }
    {
        const float4* ng = (const float4*)(nodes + (size_t)row0 * H_);
        if (t < 50) ((float4*)nod_s)[t] = ng[t];
    }
    __syncthreads();
    if (j >= H_) return;
    const float4* h4p = (const float4*)nod_s[r];
    float wa = 0.f;
#pragma unroll 5
    for (int k4 = 0; k4 < 25; ++k4) {
        const float4 h4 = h4p[k4];
        const int k = k4 * 4;
        wa = fmaf(h4.x, Ww[(k + 0) * H_ + j], wa);
        wa = fmaf(h4.y, Ww[(k + 1) * H_ + j], wa);
        wa = fmaf(h4.z, Ww[(k + 2) * H_ + j], wa);
        wa = fmaf(h4.w, Ww[(k + 3) * H_ + j], wa);
    }
    hw[(size_t)(row0 + r) * H_ + j] = wa;
}

// ---------------------------------------------------------------------------
// K2: one fused message pass (r13/r17 structure + BATCH-AFFINE SWIZZLE).
// blockIdx decode: cu = bx&255, slot = bx>>8, b = cu>>3, vt = (cu&7)+slot*8.
// Round-robin dispatch puts blocks congruent mod 256 on the same CU; under
// this decode they share one batch -> one 51 KB hw slab stays L1/L2-hot per
// CU instead of ~6 competing slabs (L1 thrash was the unexplained ~15 us of
// k_pass stall). 2 rows per 256-thread block (r = t>>7, j = t&127).
// Message loop: e_s b128 broadcast + ballot-bit SGPR mask + coalesced hw.
// MODE 1 -> tanh update + next-pass hv/hw projections; MODE 2 -> readout.
template <int MODE, int INIT_HV>
__global__ __launch_bounds__(256, 6) void k_pass(const float* __restrict__ edges,
                                                 const float* __restrict__ We,
                                                 const float* __restrict__ Wu,
                                                 const float* __restrict__ Wv,
                                                 const float* __restrict__ Ww,
                                                 const float* __restrict__ Wr,
                                                 const float* __restrict__ nodes,
                                                 float* __restrict__ hv_io,
                                                 const float* __restrict__ hw_in,
                                                 float* __restrict__ hw_out,
                                                 const float* __restrict__ hid_in,
                                                 float* __restrict__ hidden,
                                                 float* __restrict__ out) {
    __shared__ float4 e_s[2][N_];          // 4 KB
    __shared__ float  asum_part[4];        // per-wave partial row sums
    __shared__ unsigned qmask_s[2][4];     // per-row edge-mask bits (4x32)
    __shared__ float  hid_s[2][H_];
    __shared__ float  msg_s[2][H_];
    __shared__ float  hn_s[2][H_];
    __shared__ float  nod_s[2][H_];        // MODE 2 only
    __shared__ float  red_s[2][H_];        // MODE 2 only

    // batch-affine swizzle: co-resident blocks (≡ mod 256) share batch b
    const int bx = blockIdx.x;
    const int cu = bx & 255, slot = bx >> 8;
    const int b = cu >> 3;
    const int vt = (cu & 7) + slot * 8;
    const int row0 = b * N_ + vt * 2;

    const int t = threadIdx.x, r = t >> 7, j = t & 127;
    const int wv = t >> 6, lane = t & 63;
    const int row = row0 + r;
    const bool act = (j < H_);

    {   // stage both rows' edges; ballot edge-mask bits; reduce row sums
        const float4* eg = (const float4*)(edges + (size_t)row0 * N_ * 4);
        const float4 e = eg[t];                   // t == r*128 + j, coalesced
        e_s[r][j] = e;                            // wave wv, lane l -> w = (wv&1)*64 + l
        float s = (e.x + e.y) + (e.z + e.w);
        const unsigned long long bal = __ballot(s != 0.f);
        if (lane == 0) {
            qmask_s[wv >> 1][(wv & 1) * 2]     = (unsigned)bal;
            qmask_s[wv >> 1][(wv & 1) * 2 + 1] = (unsigned)(bal >> 32);
        }
#pragma unroll
        for (int off = 32; off > 0; off >>= 1) s += __shfl_down(s, off);
        if (lane == 0) asum_part[wv] = s;
    }
    {   // stage pre-update hidden rows (50 float4); nodes too if readout pass
        const float4* hg = (const float4*)(hid_in + (size_t)row0 * H_);
        if (t < 50) ((float4*)hid_s)[t] = hg[t];
        if (MODE == 2) {
            const float4* ng = (const float4*)(nodes + (size_t)row0 * H_);
            if (t < 50) ((float4*)nod_s)[t] = ng[t];
        }
    }
    __syncthreads();

    const float nm = ((asum_part[2 * r] + asum_part[2 * r + 1]) != 0.f) ? 1.f : 0.f;

    if (act) {
        float hvv;
        if (INIT_HV) {      // pass 1: hv = hid @ Wv computed in-register
            const float4* h4p = (const float4*)hid_s[r];
            float va = 0.f;
#pragma unroll 5
            for (int k4 = 0; k4 < 25; ++k4) {
                const float4 h4 = h4p[k4];
                const int k = k4 * 4;
                va = fmaf(h4.x, Wv[(k + 0) * H_ + j], va);
                va = fmaf(h4.y, Wv[(k + 1) * H_ + j], va);
                va = fmaf(h4.z, Wv[(k + 2) * H_ + j], va);
                va = fmaf(h4.w, Wv[(k + 3) * H_ + j], va);
            }
            hvv = va;
        } else {
            hvv = hv_io[(size_t)row * H_ + j];
        }
        const float we0 = We[0 * H_ + j], we1 = We[1 * H_ + j];
        const float we2 = We[2 * H_ + j], we3 = We[3 * H_ + j];
        const float* hwp = hw_in + (size_t)b * N_ * H_ + j;
        float acc = 0.f;
        for (int c = 0; c < 4; ++c) {             // 4 chunks of 32 w
            const unsigned mq =
                __builtin_amdgcn_readfirstlane(qmask_s[r][c]);  // SGPR, uniform
            const float4* ec = &e_s[r][c * 32];
            const float*  hc = hwp + (size_t)(c * 32) * H_;
#pragma unroll 8
            for (int w8 = 0; w8 < 32; ++w8) {
                const float4 e = ec[w8];          // LDS b128 broadcast
                const float  hww = hc[w8 * H_];   // coalesced; L1-hot w/ swizzle
                const float  m = ((mq >> w8) & 1u) ? 1.f : 0.f;  // SALU cselect
                float p = hvv + hww;
                p = fmaf(e.x, we0, p);
                p = fmaf(e.y, we1, p);
                p = fmaf(e.z, we2, p);
                p = fmaf(e.w, we3, p);
                acc = fmaf(m, fmaxf(p, 0.f), acc);
            }
        }
        msg_s[r][j] = acc;
    }
    __syncthreads();

    if (act) {
        const float4* h4p = (const float4*)hid_s[r];
        const float4* m4p = (const float4*)msg_s[r];
        float u = 0.f;
#pragma unroll 5
        for (int k4 = 0; k4 < 25; ++k4) {
            const float4 h4 = h4p[k4];
            const int k = k4 * 4;
            u = fmaf(h4.x, Wu[(k + 0) * H_ + j], u);
            u = fmaf(h4.y, Wu[(k + 1) * H_ + j], u);
            u = fmaf(h4.z, Wu[(k + 2) * H_ + j], u);
            u = fmaf(h4.w, Wu[(k + 3) * H_ + j], u);
        }
#pragma unroll 5
        for (int k4 = 0; k4 < 25; ++k4) {
            const float4 m4 = m4p[k4];
            const int k = H_ + k4 * 4;
            u = fmaf(m4.x, Wu[(k + 0) * H_ + j], u);
            u = fmaf(m4.y, Wu[(k + 1) * H_ + j], u);
            u = fmaf(m4.z, Wu[(k + 2) * H_ + j], u);
            u = fmaf(m4.w, Wu[(k + 3) * H_ + j], u);
        }
        const float nh = (nm != 0.f) ? tanhf(u) : hid_s[r][j];
        hn_s[r][j] = nh;
        if (MODE == 1) hidden[(size_t)row * H_ + j] = nh;
    }
    __syncthreads();

    if (MODE == 1) {        // next pass's hv/hw from fresh hidden (own rows)
        if (act) {
            const float4* h4p = (const float4*)hn_s[r];
            float va = 0.f, wa = 0.f;
#pragma unroll 5
            for (int k4 = 0; k4 < 25; ++k4) {
                const float4 h4 = h4p[k4];
                const int k = k4 * 4;
                va = fmaf(h4.x, Wv[(k + 0) * H_ + j], va);
                wa = fmaf(h4.x, Ww[(k + 0) * H_ + j], wa);
                va = fmaf(h4.y, Wv[(k + 1) * H_ + j], va);
                wa = fmaf(h4.y, Ww[(k + 1) * H_ + j], wa);
                va = fmaf(h4.z, Wv[(k + 2) * H_ + j], va);
                wa = fmaf(h4.z, Ww[(k + 2) * H_ + j], wa);
                va = fmaf(h4.w, Wv[(k + 3) * H_ + j], va);
                wa = fmaf(h4.w, Ww[(k + 3) * H_ + j], wa);
            }
            hv_io[(size_t)row * H_ + j] = va;     // row-local: safe in-place
            hw_out[(size_t)row * H_ + j] = wa;    // double-buffered
        }
    } else {                // MODE 2: fused readout
        if (act) {
            const float4* h4p = (const float4*)hn_s[r];
            const float4* n4p = (const float4*)nod_s[r];
            float u = 0.f;
#pragma unroll 5
            for (int k4 = 0; k4 < 25; ++k4) {
                const float4 h4 = h4p[k4];
                const int k = k4 * 4;
                u = fmaf(h4.x, Wr[(k + 0) * H_ + j], u);
                u = fmaf(h4.y, Wr[(k + 1) * H_ + j], u);
                u = fmaf(h4.z, Wr[(k + 2) * H_ + j], u);
                u = fmaf(h4.w, Wr[(k + 3) * H_ + j], u);
            }
#pragma unroll 5
            for (int k4 = 0; k4 < 25; ++k4) {
                const float4 n4 = n4p[k4];
                const int k = H_ + k4 * 4;
                u = fmaf(n4.x, Wr[(k + 0) * H_ + j], u);
                u = fmaf(n4.y, Wr[(k + 1) * H_ + j], u);
                u = fmaf(n4.z, Wr[(k + 2) * H_ + j], u);
                u = fmaf(n4.w, Wr[(k + 3) * H_ + j], u);
            }
            red_s[r][j] = nm * fmaxf(u, 0.f);
        }
        __syncthreads();
        if (t < H_) atomicAdd(out + b * H_ + t, red_s[0][t] + red_s[1][t]);
    }
}

// ---------------------------------------------------------------------------
extern "C" void kernel_launch(void* const* d_in, const int* in_sizes, int n_in,
                              void* d_out, int out_size, void* d_ws, size_t ws_size,
                              hipStream_t stream) {
    const float* nodes = (const float*)d_in[0];
    const float* edges = (const float*)d_in[1];
    const float* Wv    = (const float*)d_in[2];
    const float* Ww    = (const float*)d_in[3];
    const float* We    = (const float*)d_in[4];
    const float* Wu    = (const float*)d_in[5];
    const float* Wr    = (const float*)d_in[6];
    float* out = (float*)d_out;

    float* hidden = (float*)d_ws;     // RH
    float* hv     = hidden + RH;      // RH
    float* hwA    = hv + RH;          // RH
    float* hwB    = hwA + RH;         // RH

    k_proj0<<<ROWS / 2, 256, 0, stream>>>(nodes, Ww, hwA, out);

    k_pass<1, 1><<<ROWS / 2, 256, 0, stream>>>(edges, We, Wu, Wv, Ww, Wr, nodes,
                                               hv, hwA, hwB, nodes, hidden, out);
    k_pass<1, 0><<<ROWS / 2, 256, 0, stream>>>(edges, We, Wu, Wv, Ww, Wr, nodes,
                                               hv, hwB, hwA, hidden, hidden, out);
    k_pass<2, 0><<<ROWS / 2, 256, 0, stream>>>(edges, We, Wu, Wv, Ww, Wr, nodes,
                                               hv, hwA, hwB, hidden, hidden, out);
}